// Round 6
// baseline (393.106 us; speedup 1.0000x reference)
//
#include <hip/hip_runtime.h>
#include <math.h>

#define TOKENS 16384
#define DIM    4096
#define NEXP   64
#define KSPLIT 4
#define KSLICE (DIM / KSPLIT)   // 1024
#define BK     32               // k per chunk (one MFMA K=32)
#define NCHUNK (KSLICE / BK)    // 32 chunks per slice
#define QCHUNK 8                // chunks per LDS-resident B quarter (64 KB)
#define TB     128              // tokens per block (8 waves x 16 tokens)
#define NCHUNK_G (DIM / BK)     // 128 global chunks

typedef _Float16 f16x8 __attribute__((ext_vector_type(8)));
typedef float    f32x4 __attribute__((ext_vector_type(4)));

#define MFMA16(a, b, c) __builtin_amdgcn_mfma_f32_16x16x32_f16((a), (b), (c), 0, 0, 0)
#define SBAR() __builtin_amdgcn_sched_barrier(0)

// async global->LDS, 16B per lane, dest = wave-uniform base + 16*lane
__device__ __forceinline__ void gload16(const void* g, void* l) {
    __builtin_amdgcn_global_load_lds(
        (const __attribute__((address_space(1))) void*)g,
        (__attribute__((address_space(3))) void*)l, 16, 0, 0);
}

// ---------------- Kernel 0: pack W into MFMA B-fragment planes ---------------
// Layout: wpk[c=0..127][plane p=0..7][lane=0..63] x 16B. p = 2*t + h
// (t = expert tile, h = 0 hi / 1 lo). Chunk-major, plane, lane: the GEMM's
// B quarter (8 chunks = 64 KB) is one contiguous 4096-uint4 range -> staged
// with 64 perfectly-linear gload16 and read back contiguous-by-lane
// (conflict-free ds_read_b128).
// Fragment convention (matches A-side): lane l supplies B[k=8*(l>>4)+j][n=l&15],
// j=0..7, from expert row e=16t+(l&15). Lo scaled 2^16 (stays fp16-normal);
// |w|<2^-14 guarded into lo so denormal flush can't bite.
__global__ __launch_bounds__(256)
void pack_w_kernel(const float* __restrict__ w, uint4* __restrict__ wpk) {
    const int lane = threadIdx.x & 63;
    const int t    = threadIdx.x >> 6;     // expert tile 0..3
    const int c    = blockIdx.x;           // global k-chunk 0..127
    const int e    = 16 * t + (lane & 15);
    const int k0   = 32 * c + 8 * (lane >> 4);

    const float* src = w + (size_t)e * DIM + k0;
    const float4 v0 = *(const float4*)(src);
    const float4 v1 = *(const float4*)(src + 4);
    const float xs[8] = {v0.x, v0.y, v0.z, v0.w, v1.x, v1.y, v1.z, v1.w};

    f16x8 hi, lo;
#pragma unroll
    for (int j = 0; j < 8; ++j) {
        const float xv = xs[j];
        _Float16 h = (_Float16)xv;           // RNE
        float hf = (float)h;
        if (fabsf(xv) < 6.103515625e-05f) {  // below fp16 min normal: hi = 0
            h = (_Float16)0.f; hf = 0.f;
        }
        hi[j] = h;
        lo[j] = (_Float16)((xv - hf) * 65536.f);
    }

    wpk[(size_t)c * 512 + (2 * t + 0) * 64 + lane] = *(const uint4*)&hi;
    wpk[(size_t)c * 512 + (2 * t + 1) * 64 + lane] = *(const uint4*)&lo;
}

// ---------------- Kernel 1: split-K GEMM, B-persistent-in-LDS ----------------
// R6: remove B from the steady-state vmem stream. Every prior design waited
// on B-fragment loads each chunk; the in-order vmcnt queue then coupled that
// wait to outstanding X HBM misses (R2/R4), or barriered phase-lockstep ate
// the pipeline (R5's 2-phase stage/consume, cf. m233). Now:
//   - B: one k-slice quarter (8 chunks, 64 KB) persists in LDS; reloaded 3x
//     per block at uniform swap points (c=8,16,24) with a full vmcnt(0) drain
//     (~800 cyc each, amortized over 8 chunks).
//   - X: per-lane direct global->reg loads in the A-fragment layout, depth-2
//     ring (4 slots, statically indexed via unroll-4; slot = (u+2)&3 since
//     c%4==0). SBAR pins the issue 2 chunks ahead (anti-sink, the R2 bug);
//     the compiler inserts exact counted vmcnt for the ring-reg consumes.
//   - steady loop: ZERO barriers, ZERO manual waitcnt, pure X stream.
// 8 waves/block (512 thr), grid 512 = 128 strips x KSPLIT. ks = bid&3 and
// XCD = bid&7 -> each XCD serves exactly one ks -> B slice is L2-resident.
// Outstanding X per CU = 8 waves x 2 chunks x 2KB = 32KB >> BW*latency (~9KB).
__device__ __forceinline__ void split_a(const float4 lo, const float4 hi,
                                        f16x8& ah, f16x8& al) {
    const float xs[8] = {lo.x, lo.y, lo.z, lo.w, hi.x, hi.y, hi.z, hi.w};
#pragma unroll
    for (int j = 0; j < 8; ++j) {
        const float xv = xs[j];
        const _Float16 h = (_Float16)xv;               // RNE
        ah[j] = h;
        al[j] = (_Float16)((xv - (float)h) * 65536.f); // exact sub, exact *2^16
    }
}

__device__ __forceinline__ void fma3(const f16x8 ah, const f16x8 al,
                                     const f16x8 bh, const f16x8 bl,
                                     f32x4& a1, f32x4& a2) {
    a1 = MFMA16(ah, bh, a1);   // hi*hi
    a2 = MFMA16(ah, bl, a2);   // hi*lo (scaled 2^16)
    a2 = MFMA16(al, bh, a2);   // lo*hi (scaled 2^16)
}

__global__ __launch_bounds__(512)
void router_gemm_kernel(const float* __restrict__ x,
                        const uint4* __restrict__ wpk,
                        float* __restrict__ part) {
    __shared__ uint4 Blds[QCHUNK * 512];   // 8 chunks x 8 planes x 64 lanes = 64 KB

    const int tid  = threadIdx.x;
    const int lane = tid & 63;
    const int wv   = tid >> 6;              // 0..7
    const int bid  = blockIdx.x;
    const int ks   = bid & (KSPLIT - 1);    // == XCD&3 -> one ks per XCD
    const int wt0  = (bid >> 2) * TB + wv * 16;

    // A side: lane l -> token row (l&15), k dword base 8*(l>>4) within chunk
    const float* xp = x + (size_t)(wt0 + (lane & 15)) * DIM
                    + ks * KSLICE + 8 * (lane >> 4);

    // B slice base (global chunk = ks*32 + cc)
    const uint4* bsl = wpk + (size_t)ks * NCHUNK * 512 + (size_t)(wv * 8) * 64 + lane;

    // stage one 64 KB quarter q: 8 gloads/wave, linear (chunk,plane,lane) order
    auto STAGE_B = [&](int q) {
        const uint4* src = bsl + (size_t)q * QCHUNK * 512;
#pragma unroll
        for (int i = 0; i < 8; ++i)
            gload16(src + i * 64, &Blds[(wv * 8 + i) * 64]);
    };

    f32x4 a10, a11, a12, a13, a20, a21, a22, a23;
    const f32x4 zero = {0.f, 0.f, 0.f, 0.f};
    a10 = a11 = a12 = a13 = zero;
    a20 = a21 = a22 = a23 = zero;

    float4 rl[4], rh[4];   // X ring, statically indexed (unroll-4, c%4==0)

    // prologue: B quarter 0 + X chunks 0,1; one-time full drain
    STAGE_B(0);
    rl[0] = *(const float4*)(xp);
    rh[0] = *(const float4*)(xp + 4);
    rl[1] = *(const float4*)(xp + BK);
    rh[1] = *(const float4*)(xp + BK + 4);
    asm volatile("s_waitcnt vmcnt(0)" ::: "memory");
    __builtin_amdgcn_s_barrier();

#pragma unroll 1
    for (int c = 0; c < NCHUNK; c += 4) {
        if (c && (c & (QCHUNK - 1)) == 0) {   // c = 8, 16, 24: B quarter swap
            asm volatile("s_waitcnt lgkmcnt(0)" ::: "memory");
            __builtin_amdgcn_s_barrier();      // all waves done reading old B
            STAGE_B(c >> 3);
            asm volatile("s_waitcnt vmcnt(0)" ::: "memory");  // B (+2 X) landed
            __builtin_amdgcn_s_barrier();      // all waves' B staged
        }
#pragma unroll
        for (int u = 0; u < 4; ++u) {
            const int cc = c + u;
            SBAR();
            {   // issue X(cc+2) into slot (u+2)&3 -- 2-chunk lead, pinned
                const int cn = (cc + 2) & (NCHUNK - 1);   // tail wrap, in-bounds
                rl[(u + 2) & 3] = *(const float4*)(xp + cn * BK);
                rh[(u + 2) & 3] = *(const float4*)(xp + cn * BK + 4);
            }
            SBAR();
            // consume chunk cc: B from persistent LDS, X from ring slot u
            const uint4* Br = &Blds[((cc & (QCHUNK - 1)) * 8) * 64];
            f16x8 ah, al;
            split_a(rl[u], rh[u], ah, al);    // compiler-counted vmcnt wait
            {   // tiles 0,1 (B-live kept to 16 VGPR)
                const f16x8 bh0 = *(const f16x8*)&Br[0 * 64 + lane];
                const f16x8 bl0 = *(const f16x8*)&Br[1 * 64 + lane];
                const f16x8 bh1 = *(const f16x8*)&Br[2 * 64 + lane];
                const f16x8 bl1 = *(const f16x8*)&Br[3 * 64 + lane];
                fma3(ah, al, bh0, bl0, a10, a20);
                fma3(ah, al, bh1, bl1, a11, a21);
            }
            {   // tiles 2,3
                const f16x8 bh2 = *(const f16x8*)&Br[4 * 64 + lane];
                const f16x8 bl2 = *(const f16x8*)&Br[5 * 64 + lane];
                const f16x8 bh3 = *(const f16x8*)&Br[6 * 64 + lane];
                const f16x8 bl3 = *(const f16x8*)&Br[7 * 64 + lane];
                fma3(ah, al, bh2, bl2, a12, a22);
                fma3(ah, al, bh3, bl3, a13, a23);
            }
        }
    }

    // Epilogue: D lane map (HW-verified): m = 4*(l>>4)+rr, n = l&15.
    float* pout = part + ((size_t)ks * TOKENS + wt0 + 4 * (lane >> 4)) * NEXP
                + (lane & 15);
    const f32x4 v0 = a10 + a20 * (1.f / 65536.f);
    const f32x4 v1 = a11 + a21 * (1.f / 65536.f);
    const f32x4 v2 = a12 + a22 * (1.f / 65536.f);
    const f32x4 v3 = a13 + a23 * (1.f / 65536.f);
#pragma unroll
    for (int rr = 0; rr < 4; ++rr) {
        pout[(size_t)rr * NEXP +  0] = v0[rr];
        pout[(size_t)rr * NEXP + 16] = v1[rr];
        pout[(size_t)rr * NEXP + 32] = v2[rr];
        pout[(size_t)rr * NEXP + 48] = v3[rr];
    }
}

// ---------------- Kernel 2: split-K reduce + top-2 + softmax ----------------
// One wave per token; lane == expert. Butterfly argmax twice (tiebreak: lower
// index). Indices written as float (harness reads d_out via the fp32 path).
__global__ __launch_bounds__(256)
void topk_kernel(const float* __restrict__ part, float* __restrict__ out) {
    const int lane  = threadIdx.x & 63;
    const int wv    = threadIdx.x >> 6;
    const int token = blockIdx.x * 4 + wv;

    float logit = 0.f;
#pragma unroll
    for (int s = 0; s < KSPLIT; ++s)
        logit += part[((size_t)s * TOKENS + token) * NEXP + lane];

    // top-1
    float v1 = logit; int i1 = lane;
#pragma unroll
    for (int off = 32; off > 0; off >>= 1) {
        const float ov = __shfl_xor(v1, off);
        const int   oi = __shfl_xor(i1, off);
        if (ov > v1 || (ov == v1 && oi < i1)) { v1 = ov; i1 = oi; }
    }
    // top-2: mask the winner
    float v2 = (lane == i1) ? -INFINITY : logit; int i2 = lane;
#pragma unroll
    for (int off = 32; off > 0; off >>= 1) {
        const float ov = __shfl_xor(v2, off);
        const int   oi = __shfl_xor(i2, off);
        if (ov > v2 || (ov == v2 && oi < i2)) { v2 = ov; i2 = oi; }
    }

    if (lane == 0) {
        const float e = expf(v2 - v1);       // <= 1, no overflow
        const float r = 1.f / (1.f + e);
        out[2 * token + 0] = r;              // score of top-1
        out[2 * token + 1] = e * r;          // score of top-2
        out[2 * TOKENS + 2 * token + 0] = (float)i1;
        out[2 * TOKENS + 2 * token + 1] = (float)i2;
    }
}

extern "C" void kernel_launch(void* const* d_in, const int* in_sizes, int n_in,
                              void* d_out, int out_size, void* d_ws, size_t ws_size,
                              hipStream_t stream) {
    const float* x = (const float*)d_in[0];   // (4,4096,4096) fp32
    const float* w = (const float*)d_in[1];   // (64,4096) fp32
    float* out  = (float*)d_out;              // 32768 scores + 32768 float-encoded indices
    float* part = (float*)d_ws;               // KSPLIT*TOKENS*NEXP*4 = 16.8 MB
    // packed W fragment planes right after part: 128*8*64*16B = 1 MB
    uint4* wpk = (uint4*)((char*)d_ws + (size_t)KSPLIT * TOKENS * NEXP * sizeof(float));

    pack_w_kernel<<<NCHUNK_G, 256, 0, stream>>>(w, wpk);
    router_gemm_kernel<<<(TOKENS / TB) * KSPLIT, 512, 0, stream>>>(x, wpk, part);
    topk_kernel<<<TOKENS / 4, 256, 0, stream>>>(part, out);
}

// Round 8
// 385.188 us; speedup vs baseline: 1.0206x; 1.0206x over previous
//
#include <hip/hip_runtime.h>
#include <math.h>

#define TOKENS 16384
#define DIM    4096
#define NEXP   64
#define KSPLIT 4
#define KSLICE (DIM / KSPLIT)   // 1024
#define BK     32               // k per chunk (one MFMA K=32)
#define NCHUNK (KSLICE / BK)    // 32 chunks per slice
#define TB     128              // tokens per block (8 waves, 2x2 tile ownership)
#define NCHUNK_G (DIM / BK)     // 128 global chunks

typedef _Float16 f16x8 __attribute__((ext_vector_type(8)));
typedef float    f32x4 __attribute__((ext_vector_type(4)));

#define MFMA16(a, b, c) __builtin_amdgcn_mfma_f32_16x16x32_f16((a), (b), (c), 0, 0, 0)

// async global->LDS, 16B per lane, dest = wave-uniform base + 16*lane
__device__ __forceinline__ void gload16(const void* g, void* l) {
    __builtin_amdgcn_global_load_lds(
        (const __attribute__((address_space(1))) void*)g,
        (__attribute__((address_space(3))) void*)l, 16, 0, 0);
}

// ---------------- Kernel 0: pack W into MFMA B-fragment planes ---------------
// Layout: wpk[c=0..127][plane p=0..7][lane=0..63] x 16B. p = 2*t + h
// (t = expert tile, h = 0 hi / 1 lo). Plane = 1KB contiguous-by-lane: staged
// with one linear gload16 and read back contiguous-by-lane (conflict-free).
// Fragment convention (matches A-side): lane l supplies B[k=8*(l>>4)+j][n=l&15],
// j=0..7, from expert row e=16t+(l&15). Lo scaled 2^16 (stays fp16-normal);
// |w|<2^-14 guarded into lo so denormal flush can't bite.
__global__ __launch_bounds__(256)
void pack_w_kernel(const float* __restrict__ w, uint4* __restrict__ wpk) {
    const int lane = threadIdx.x & 63;
    const int t    = threadIdx.x >> 6;     // expert tile 0..3
    const int c    = blockIdx.x;           // global k-chunk 0..127
    const int e    = 16 * t + (lane & 15);
    const int k0   = 32 * c + 8 * (lane >> 4);

    const float* src = w + (size_t)e * DIM + k0;
    const float4 v0 = *(const float4*)(src);
    const float4 v1 = *(const float4*)(src + 4);
    const float xs[8] = {v0.x, v0.y, v0.z, v0.w, v1.x, v1.y, v1.z, v1.w};

    f16x8 hi, lo;
#pragma unroll
    for (int j = 0; j < 8; ++j) {
        const float xv = xs[j];
        _Float16 h = (_Float16)xv;           // RNE
        float hf = (float)h;
        if (fabsf(xv) < 6.103515625e-05f) {  // below fp16 min normal: hi = 0
            h = (_Float16)0.f; hf = 0.f;
        }
        hi[j] = h;
        lo[j] = (_Float16)((xv - hf) * 65536.f);
    }

    wpk[(size_t)c * 512 + (2 * t + 0) * 64 + lane] = *(const uint4*)&hi;
    wpk[(size_t)c * 512 + (2 * t + 1) * 64 + lane] = *(const uint4*)&lo;
}

// ---------------- Kernel 1: split-K GEMM, deep-lead LDS pipeline -------------
// R8 = R7 with the WAR race fixed. R7 dropped R5's trailing barrier; with one
// barrier/iter, iter c's stage-issues and iter c-1's consumes share an
// inter-barrier window, so a fast wave's async gload_lds write (B slot
// (c+1)&1 == chunk c-1's slot; X slot (c+3)&3 == chunk c-1's slot) lands
// while a slow wave still ds_reads chunk c-1 -> corrupted operands -> wrong
// argmax (absmax 61 on indices). The trailing {lgkmcnt(0); s_barrier} (as in
// passing R5) guarantees all reads of window-c buffers complete before any
// wave issues window-c+1 overwrites; with it, ring depths (B=2, X=4) satisfy
// last-read(iter<=c-1) vs write-issue(iter c).
// Kept from R7:
//  (1) DRAM row locality: X staged 2 chunks per stage-op, plane-adjacent
//      issue -> each row's two ADJACENT 128B lines issue back-to-back ->
//      row-buffer hit (prior rounds: single 128B granules ~2000cy apart,
//      ~35% DRAM eff = the 2.2 TB/s plateau).
//  (2) deep counted lead: 4-slot X ring + 2-slot B ring, uniform vmcnt(5),
//      B issued BEFORE X so the in-order queue never force-drains the X lead.
//      B-lead 1 iter, X-lead 2-3 iters, never vmcnt(0).
// 8-wave blocks (TB=128), wave = (tf,et) in 4x2: owns token-frags {2tf,2tf+1}
// x expert-tiles {2et,2et+1} -> B reads amortize over 2 frags (8KB/wave/iter).
// LDS 80KB/block -> 2 blocks/CU (16 waves). T5 setprio around MFMA cluster.
__device__ __forceinline__ void split_a(const f32x4 lo, const f32x4 hi,
                                        f16x8& ah, f16x8& al) {
    const float xs[8] = {lo[0], lo[1], lo[2], lo[3], hi[0], hi[1], hi[2], hi[3]};
#pragma unroll
    for (int j = 0; j < 8; ++j) {
        const float xv = xs[j];
        const _Float16 h = (_Float16)xv;               // RNE
        ah[j] = h;
        al[j] = (_Float16)((xv - (float)h) * 65536.f); // exact sub, exact *2^16
    }
}

__device__ __forceinline__ void fma3(const f16x8 ah, const f16x8 al,
                                     const f16x8 bh, const f16x8 bl,
                                     f32x4& a1, f32x4& a2) {
    a1 = MFMA16(ah, bh, a1);   // hi*hi
    a2 = MFMA16(ah, bl, a2);   // hi*lo (scaled 2^16)
    a2 = MFMA16(al, bh, a2);   // lo*hi (scaled 2^16)
}

__global__ __launch_bounds__(512)
__attribute__((amdgpu_waves_per_eu(4, 4)))
void router_gemm_kernel(const float* __restrict__ x,
                        const uint4* __restrict__ wpk,
                        float* __restrict__ part) {
    // X: 4 slots x 1024 uint4 (16KB each); B: 2 slots x 512 uint4 (8KB each)
    __shared__ uint4 lds[5120];   // 80 KB

    const int tid  = threadIdx.x;
    const int lane = tid & 63;
    const int wv   = tid >> 6;              // 0..7
    const int tf   = wv >> 1;               // token-frag pair 0..3
    const int et   = wv & 1;                // expert-tile pair 0..1
    const int bid  = blockIdx.x;
    const int ks   = bid & (KSPLIT - 1);
    const int token0 = (bid >> 2) * TB;

    // ---- stage-side addressing: wave stages its OWN rows 16wv..16wv+15 ----
    // plane q (8 rows): lane l -> row rl=l>>3, 16B-block sb=(l&7)^rl (inverse
    // swizzle on the global source; LDS dest linear).
    const int rl = lane >> 3;
    const int sb = (lane & 7) ^ rl;
    const float* xsrc0 = x + (size_t)(token0 + 16 * wv + rl) * DIM
                       + ks * KSLICE + 4 * sb;
    const float* xsrc1 = xsrc0 + (size_t)8 * DIM;
    // B: wave stages plane wv of each chunk (per-lane contiguous 16B)
    const uint4* bsrc = wpk + (size_t)(ks * NCHUNK) * 512 + wv * 64 + lane;

    // ---- consume-side addressing ----
    const int xib = ((lane >> 3) & 1) * 64 + (lane & 7) * 8;  // plane + row-in-plane
    const int xk0 = (2 * (lane >> 4)    ) ^ (lane & 7);       // swizzled 16B-block
    const int xk1 = (2 * (lane >> 4) + 1) ^ (lane & 7);

    f32x4 a1[2][2], a2[2][2];
    const f32x4 zero = {0.f, 0.f, 0.f, 0.f};
#pragma unroll
    for (int f = 0; f < 2; ++f)
#pragma unroll
        for (int e = 0; e < 2; ++e) { a1[f][e] = zero; a2[f][e] = zero; }

    // ---- prologue: X(0),X(1) then B(0) ----
    gload16(xsrc0,          &lds[0 * 1024 + wv * 128]);
    gload16(xsrc0 + BK,     &lds[1 * 1024 + wv * 128]);
    gload16(xsrc1,          &lds[0 * 1024 + wv * 128 + 64]);
    gload16(xsrc1 + BK,     &lds[1 * 1024 + wv * 128 + 64]);
    gload16(bsrc,           &lds[4096 + 0 * 512 + wv * 64]);

#pragma unroll 1
    for (int c = 0; c < NCHUNK; ++c) {
        // ---- stage issues: B(c+1) FIRST, then X pair on even iters ----
        {
            const int cb = (c + 1) & (NCHUNK - 1);     // tail wrap, in-bounds
            gload16(bsrc + (size_t)cb * 512,
                    &lds[4096 + ((c + 1) & 1) * 512 + wv * 64]);
        }
        if (!(c & 1)) {
            const int c2 = (c + 2) & (NCHUNK - 1);
            const int c3 = (c + 3) & (NCHUNK - 1);
            uint4* d2 = &lds[((c + 2) & 3) * 1024 + wv * 128];
            uint4* d3 = &lds[((c + 3) & 3) * 1024 + wv * 128];
            // plane0 of both chunks back-to-back: same 8 rows, ADJACENT 128B
            // lines -> DRAM row-buffer hit on the second access.
            gload16(xsrc0 + c2 * BK, d2);
            gload16(xsrc0 + c3 * BK, d3);
            gload16(xsrc1 + c2 * BK, d2 + 64);
            gload16(xsrc1 + c3 * BK, d3 + 64);
        }
        // counted wait: retires through B(c) (and thus X(c), older in queue);
        // leaves exactly 5 in flight (B(c+1) + 4 X) on every iteration.
        asm volatile("s_waitcnt vmcnt(5)" ::: "memory");
        __builtin_amdgcn_s_barrier();                  // all waves' c staged

        const uint4* Xr = &lds[(c & 3) * 1024];
        const uint4* Br = &lds[4096 + (c & 1) * 512];

        // A-frags: global frag gf = 2tf+f -> rows gf*16 + (lane&15)
        f16x8 ah0, al0, ah1, al1;
        {
            const int b0 = (2 * tf + 0) * 128 + xib;
            const int b1 = (2 * tf + 1) * 128 + xib;
            const f32x4 A0l = *(const f32x4*)&Xr[b0 + xk0];
            const f32x4 A0h = *(const f32x4*)&Xr[b0 + xk1];
            const f32x4 A1l = *(const f32x4*)&Xr[b1 + xk0];
            const f32x4 A1h = *(const f32x4*)&Xr[b1 + xk1];
            split_a(A0l, A0h, ah0, al0);
            split_a(A1l, A1h, ah1, al1);
        }
        // B-tiles: global tile ge = 2et+e -> planes 2ge (hi), 2ge+1 (lo)
        const f16x8 bh0 = *(const f16x8*)&Br[(4 * et + 0) * 64 + lane];
        const f16x8 bl0 = *(const f16x8*)&Br[(4 * et + 1) * 64 + lane];
        const f16x8 bh1 = *(const f16x8*)&Br[(4 * et + 2) * 64 + lane];
        const f16x8 bl1 = *(const f16x8*)&Br[(4 * et + 3) * 64 + lane];

        __builtin_amdgcn_s_setprio(1);
        fma3(ah0, al0, bh0, bl0, a1[0][0], a2[0][0]);
        fma3(ah0, al0, bh1, bl1, a1[0][1], a2[0][1]);
        fma3(ah1, al1, bh0, bl0, a1[1][0], a2[1][0]);
        fma3(ah1, al1, bh1, bl1, a1[1][1], a2[1][1]);
        __builtin_amdgcn_s_setprio(0);

        // ---- WAR fence (the R7 bug fix): all waves' ds_reads of window-c
        // buffers must complete before anyone issues window-c+1 overwrites.
        asm volatile("s_waitcnt lgkmcnt(0)" ::: "memory");
        __builtin_amdgcn_s_barrier();
    }

    // Epilogue: D lane map (HW-verified): m = 4*(l>>4)+rr, n = l&15.
    // token = token0 + (2tf+f)*16 + m ; expert = 16*(2et+e) + (l&15)
#pragma unroll
    for (int f = 0; f < 2; ++f) {
#pragma unroll
        for (int e = 0; e < 2; ++e) {
            const f32x4 v = a1[f][e] + a2[f][e] * (1.f / 65536.f);
            float* pout = part
                + ((size_t)ks * TOKENS + token0 + (2 * tf + f) * 16
                   + 4 * (lane >> 4)) * NEXP
                + 16 * (2 * et + e) + (lane & 15);
#pragma unroll
            for (int rr = 0; rr < 4; ++rr)
                pout[(size_t)rr * NEXP] = v[rr];
        }
    }
}

// ---------------- Kernel 2: split-K reduce + top-2 + softmax ----------------
// One wave per token; lane == expert. Butterfly argmax twice (tiebreak: lower
// index). Indices written as float (harness reads d_out via the fp32 path).
__global__ __launch_bounds__(256)
void topk_kernel(const float* __restrict__ part, float* __restrict__ out) {
    const int lane  = threadIdx.x & 63;
    const int wv    = threadIdx.x >> 6;
    const int token = blockIdx.x * 4 + wv;

    float logit = 0.f;
#pragma unroll
    for (int s = 0; s < KSPLIT; ++s)
        logit += part[((size_t)s * TOKENS + token) * NEXP + lane];

    // top-1
    float v1 = logit; int i1 = lane;
#pragma unroll
    for (int off = 32; off > 0; off >>= 1) {
        const float ov = __shfl_xor(v1, off);
        const int   oi = __shfl_xor(i1, off);
        if (ov > v1 || (ov == v1 && oi < i1)) { v1 = ov; i1 = oi; }
    }
    // top-2: mask the winner
    float v2 = (lane == i1) ? -INFINITY : logit; int i2 = lane;
#pragma unroll
    for (int off = 32; off > 0; off >>= 1) {
        const float ov = __shfl_xor(v2, off);
        const int   oi = __shfl_xor(i2, off);
        if (ov > v2 || (ov == v2 && oi < i2)) { v2 = ov; i2 = oi; }
    }

    if (lane == 0) {
        const float e = expf(v2 - v1);       // <= 1, no overflow
        const float r = 1.f / (1.f + e);
        out[2 * token + 0] = r;              // score of top-1
        out[2 * token + 1] = e * r;          // score of top-2
        out[2 * TOKENS + 2 * token + 0] = (float)i1;
        out[2 * TOKENS + 2 * token + 1] = (float)i2;
    }
}

extern "C" void kernel_launch(void* const* d_in, const int* in_sizes, int n_in,
                              void* d_out, int out_size, void* d_ws, size_t ws_size,
                              hipStream_t stream) {
    const float* x = (const float*)d_in[0];   // (4,4096,4096) fp32
    const float* w = (const float*)d_in[1];   // (64,4096) fp32
    float* out  = (float*)d_out;              // 32768 scores + 32768 float-encoded indices
    float* part = (float*)d_ws;               // KSPLIT*TOKENS*NEXP*4 = 16.8 MB
    // packed W fragment planes right after part: 128*8*64*16B = 1 MB
    uint4* wpk = (uint4*)((char*)d_ws + (size_t)KSPLIT * TOKENS * NEXP * sizeof(float));

    pack_w_kernel<<<NCHUNK_G, 256, 0, stream>>>(w, wpk);
    router_gemm_kernel<<<(TOKENS / TB) * KSPLIT, 512, 0, stream>>>(x, wpk, part);
    topk_kernel<<<TOKENS / 4, 256, 0, stream>>>(part, out);
}

// Round 9
// 371.503 us; speedup vs baseline: 1.0581x; 1.0368x over previous
//
#include <hip/hip_runtime.h>
#include <math.h>

#define TOKENS 16384
#define DIM    4096
#define NEXP   64
#define KSPLIT 4
#define KSLICE (DIM / KSPLIT)   // 1024 floats per row per slice
#define BK     32               // k floats per chunk (one MFMA K=32)
#define NCHUNK (KSLICE / BK)    // 32 chunks per slice
#define GROUP  4                // chunks per X stage-group: 512 B per row per touch
#define NGROUP (NCHUNK / GROUP) // 8 groups
#define TB     64               // tokens per block
#define NCHUNK_G (DIM / BK)     // 128 global chunks (pack kernel)

typedef _Float16 f16x8 __attribute__((ext_vector_type(8)));
typedef float    f32x4 __attribute__((ext_vector_type(4)));

#define MFMA16(a, b, c) __builtin_amdgcn_mfma_f32_16x16x32_f16((a), (b), (c), 0, 0, 0)

// async global->LDS, 16B per lane, dest = wave-uniform base + 16*lane
__device__ __forceinline__ void gload16(const void* g, void* l) {
    __builtin_amdgcn_global_load_lds(
        (const __attribute__((address_space(1))) void*)g,
        (__attribute__((address_space(3))) void*)l, 16, 0, 0);
}

// ---------------- Kernel 0: pack W into MFMA B-fragment planes ---------------
// Layout: wpk[c=0..127][plane p=0..7][lane=0..63] x 16B. p = 2*t + h
// (t = expert tile, h = 0 hi / 1 lo). Plane = 1KB contiguous-by-lane: staged
// with one linear gload16 and read back contiguous-by-lane (conflict-free).
// Fragment convention (matches A-side): lane l supplies B[k=8*(l>>4)+j][n=l&15],
// j=0..7, from expert row e=16t+(l&15). Lo scaled 2^16 (stays fp16-normal);
// |w|<2^-14 guarded into lo so denormal flush can't bite.
__global__ __launch_bounds__(256)
void pack_w_kernel(const float* __restrict__ w, uint4* __restrict__ wpk) {
    const int lane = threadIdx.x & 63;
    const int t    = threadIdx.x >> 6;     // expert tile 0..3
    const int c    = blockIdx.x;           // global k-chunk 0..127
    const int e    = 16 * t + (lane & 15);
    const int k0   = 32 * c + 8 * (lane >> 4);

    const float* src = w + (size_t)e * DIM + k0;
    const float4 v0 = *(const float4*)(src);
    const float4 v1 = *(const float4*)(src + 4);
    const float xs[8] = {v0.x, v0.y, v0.z, v0.w, v1.x, v1.y, v1.z, v1.w};

    f16x8 hi, lo;
#pragma unroll
    for (int j = 0; j < 8; ++j) {
        const float xv = xs[j];
        _Float16 h = (_Float16)xv;           // RNE
        float hf = (float)h;
        if (fabsf(xv) < 6.103515625e-05f) {  // below fp16 min normal: hi = 0
            h = (_Float16)0.f; hf = 0.f;
        }
        hi[j] = h;
        lo[j] = (_Float16)((xv - hf) * 65536.f);
    }

    wpk[(size_t)c * 512 + (2 * t + 0) * 64 + lane] = *(const uint4*)&hi;
    wpk[(size_t)c * 512 + (2 * t + 1) * 64 + lane] = *(const uint4*)&lo;
}

// ---------------- Kernel 1: split-K GEMM, 512B-granule X staging -------------
// R9: attack the DRAM activation wall. R2-R8 (six schedules) all plateau at
// ~2.2 TB/s; their shared invariant is 128B-per-row touch granules on 16KB-
// strided rows -> ~50k concurrently-active DRAM rows on ~1-2k banks -> every
// access pays activate/precharge (~30% DRAM eff). Now each row's k-slice is
// read 512 B AT A TIME (4 adjacent lines, one burst):
//   - X: staged per 4-chunk GROUP: 64 rows x 512 B = 32 KB, double-buffered.
//     One gload16 covers TWO whole rows' 512 B (lanes 0-31 / 32-63), source
//     block-swizzled (li ^ row&7 within 128B) so consume ds_read_b128 is
//     bank-structural-optimal; LDS dest linear (rule 21).
//   - B: whole-group batch (4 chunks) issued at group top BEFORE the X batch;
//     8-slot ring (64 KB). This order keeps the in-order vmcnt queue aligned:
//     within a group every B(c) wait retires only B's -- X's deep lead is
//     never force-drained (the R2/R4 failure).
//   - waits: derived table vmcnt(8,7,6,5) at offsets 0..3; never 0 in loop.
//     X-lead = 1 full group (~3300 cy >> 900 cy HBM); B-lead >= 1 chunk
//     (~800 cy > L2 ~300 cy).
//   - R8's proven two-barrier skeleton per chunk kept verbatim (WAR safety:
//     all ring/buffer overwrite targets had their last reader complete at a
//     preceding trailing barrier).
// LDS 128 KB -> 1 block/CU; 8 waves = 4 token-frags x 2 expert-halves; grid
// 1024 = 256 strips x KSPLIT (4 generations); bid&7=XCD, ks=bid&3 -> one ks
// per XCD -> B slice (1 MB) L2-resident.
__device__ __forceinline__ void split_a(const f32x4 lo, const f32x4 hi,
                                        f16x8& ah, f16x8& al) {
    const float xs[8] = {lo[0], lo[1], lo[2], lo[3], hi[0], hi[1], hi[2], hi[3]};
#pragma unroll
    for (int j = 0; j < 8; ++j) {
        const float xv = xs[j];
        const _Float16 h = (_Float16)xv;               // RNE
        ah[j] = h;
        al[j] = (_Float16)((xv - (float)h) * 65536.f); // exact sub, exact *2^16
    }
}

__device__ __forceinline__ void fma3(const f16x8 ah, const f16x8 al,
                                     const f16x8 bh, const f16x8 bl,
                                     f32x4& a1, f32x4& a2) {
    a1 = MFMA16(ah, bh, a1);   // hi*hi
    a2 = MFMA16(ah, bl, a2);   // hi*lo (scaled 2^16)
    a2 = MFMA16(al, bh, a2);   // lo*hi (scaled 2^16)
}

__global__ __launch_bounds__(512)
void router_gemm_kernel(const float* __restrict__ x,
                        const uint4* __restrict__ wpk,
                        float* __restrict__ part) {
    // X: [0,4096) = 2 bufs x 64 rows x 32 blocks (64 KB)
    // B: [4096,8192) = 8 ring slots x 512 (64 KB)
    __shared__ uint4 lds[8192];

    const int tid  = threadIdx.x;
    const int lane = tid & 63;
    const int wv   = tid >> 6;              // 0..7
    const int tf   = wv >> 1;               // token-frag 0..3
    const int et   = wv & 1;                // expert half 0..1
    const int bid  = blockIdx.x;
    const int ks   = bid & (KSPLIT - 1);
    const int t0   = (bid >> 2) * TB;

    // ---- X stage addressing: wave stages rows 8wv..8wv+7; gload i covers
    // rows 8wv+2i+half (half=lane>>5), 512 B each, block-swizzled source.
    const int half = lane >> 5;
    const int li   = lane & 31;
    const float* xs_[4];
#pragma unroll
    for (int i = 0; i < 4; ++i) {
        const int rlow = 2 * i + half;            // row & 7
        xs_[i] = x + (size_t)(t0 + 8 * wv + rlow) * DIM + ks * KSLICE
               + 4 * (li ^ rlow);
    }
    // B stage: wave stages plane wv (1 KB contiguous per chunk)
    const uint4* bsrc = wpk + (size_t)(ks * NCHUNK) * 512 + wv * 64 + lane;

    // ---- consume addressing ----
    const int R   = 16 * tf + (lane & 15);    // token row in block
    const int hi4 = (lane >> 4) & 3;
    const int s3  = lane & 7;                 // == R & 7

    f32x4 a1[2], a2[2];
    const f32x4 zero = {0.f, 0.f, 0.f, 0.f};
    a1[0] = a1[1] = zero; a2[0] = a2[1] = zero;

    auto STAGE_X = [&](int g) {               // group g -> buf g&1
        uint4* d = &lds[(g & 1) * 2048 + (8 * wv) * 32];
        const int go = (g & (NGROUP - 1)) * (GROUP * BK);   // float offset: g*128
#pragma unroll
        for (int i = 0; i < 4; ++i)
            gload16(xs_[i] + go, d + i * 64);
    };
    auto STAGE_B = [&](int cb) {              // chunk cb -> ring slot cb&7
        const int c = cb & (NCHUNK - 1);
        gload16(bsrc + (size_t)c * 512, &lds[4096 + (c & 7) * 512 + wv * 64]);
    };

    // ---- prologue: X group 0 + B chunk 0; one-time full drain ----
    STAGE_X(0);
    STAGE_B(0);
    asm volatile("s_waitcnt vmcnt(0)" ::: "memory");
    __builtin_amdgcn_s_barrier();

    // per-chunk body; o compile-time (unrolled), VM = literal counted wait
#define CHUNK_O(o, VMASM)                                                     \
    do {                                                                      \
        asm volatile(VMASM ::: "memory");                                     \
        __builtin_amdgcn_s_barrier();                                         \
        const uint4* Xr = &lds[(g & 1) * 2048 + R * 32];                      \
        const uint4* Br = &lds[4096 + ((4 * g + (o)) & 7) * 512];             \
        const f32x4 Alo = *(const f32x4*)&Xr[(8 * (o) + 2 * hi4 + 0) ^ s3];   \
        const f32x4 Ahi = *(const f32x4*)&Xr[(8 * (o) + 2 * hi4 + 1) ^ s3];   \
        f16x8 ah, al;                                                         \
        split_a(Alo, Ahi, ah, al);                                            \
        const f16x8 bh0 = *(const f16x8*)&Br[(4 * et + 0) * 64 + lane];       \
        const f16x8 bl0 = *(const f16x8*)&Br[(4 * et + 1) * 64 + lane];       \
        const f16x8 bh1 = *(const f16x8*)&Br[(4 * et + 2) * 64 + lane];       \
        const f16x8 bl1 = *(const f16x8*)&Br[(4 * et + 3) * 64 + lane];       \
        __builtin_amdgcn_s_setprio(1);                                        \
        fma3(ah, al, bh0, bl0, a1[0], a2[0]);                                 \
        fma3(ah, al, bh1, bl1, a1[1], a2[1]);                                 \
        __builtin_amdgcn_s_setprio(0);                                        \
        asm volatile("s_waitcnt lgkmcnt(0)" ::: "memory");                    \
        __builtin_amdgcn_s_barrier();                                         \
    } while (0)

#pragma unroll 1
    for (int g = 0; g < NGROUP; ++g) {
        // group-top issues: B batch for the WHOLE group first, then X(g+1).
        // Queue stays [B(4g+1..4g+4), X(g+1)x4]; waits below retire only the
        // oldest B (and, at o=0, the previous X group) -- X lead preserved.
        STAGE_B(4 * g + 1);
        STAGE_B(4 * g + 2);
        STAGE_B(4 * g + 3);
        STAGE_B(4 * g + 4);       // last-group wrap: dead in-bounds prefetch
        STAGE_X(g + 1);           // g=7 wraps to group 0 / buf 0: dead, safe
        CHUNK_O(0, "s_waitcnt vmcnt(8)");   // retires B(4g) + X(g)x4
        CHUNK_O(1, "s_waitcnt vmcnt(7)");   // retires B(4g+1)
        CHUNK_O(2, "s_waitcnt vmcnt(6)");   // retires B(4g+2)
        CHUNK_O(3, "s_waitcnt vmcnt(5)");   // retires B(4g+3); 5 stay in flight
    }
#undef CHUNK_O

    // Epilogue: D lane map (HW-verified): m = 4*(l>>4)+rr, n = l&15.
    // token = t0 + 16tf + m ; expert = 16*(2et+e) + (l&15)
#pragma unroll
    for (int e = 0; e < 2; ++e) {
        const f32x4 v = a1[e] + a2[e] * (1.f / 65536.f);
        float* pout = part
            + ((size_t)ks * TOKENS + t0 + 16 * tf + 4 * (lane >> 4)) * NEXP
            + 16 * (2 * et + e) + (lane & 15);
#pragma unroll
        for (int rr = 0; rr < 4; ++rr)
            pout[(size_t)rr * NEXP] = v[rr];
    }
}

// ---------------- Kernel 2: split-K reduce + top-2 + softmax ----------------
// One wave per token; lane == expert. Butterfly argmax twice (tiebreak: lower
// index). Indices written as float (harness reads d_out via the fp32 path).
__global__ __launch_bounds__(256)
void topk_kernel(const float* __restrict__ part, float* __restrict__ out) {
    const int lane  = threadIdx.x & 63;
    const int wv    = threadIdx.x >> 6;
    const int token = blockIdx.x * 4 + wv;

    float logit = 0.f;
#pragma unroll
    for (int s = 0; s < KSPLIT; ++s)
        logit += part[((size_t)s * TOKENS + token) * NEXP + lane];

    // top-1
    float v1 = logit; int i1 = lane;
#pragma unroll
    for (int off = 32; off > 0; off >>= 1) {
        const float ov = __shfl_xor(v1, off);
        const int   oi = __shfl_xor(i1, off);
        if (ov > v1 || (ov == v1 && oi < i1)) { v1 = ov; i1 = oi; }
    }
    // top-2: mask the winner
    float v2 = (lane == i1) ? -INFINITY : logit; int i2 = lane;
#pragma unroll
    for (int off = 32; off > 0; off >>= 1) {
        const float ov = __shfl_xor(v2, off);
        const int   oi = __shfl_xor(i2, off);
        if (ov > v2 || (ov == v2 && oi < i2)) { v2 = ov; i2 = oi; }
    }

    if (lane == 0) {
        const float e = expf(v2 - v1);       // <= 1, no overflow
        const float r = 1.f / (1.f + e);
        out[2 * token + 0] = r;              // score of top-1
        out[2 * token + 1] = e * r;          // score of top-2
        out[2 * TOKENS + 2 * token + 0] = (float)i1;
        out[2 * TOKENS + 2 * token + 1] = (float)i2;
    }
}

extern "C" void kernel_launch(void* const* d_in, const int* in_sizes, int n_in,
                              void* d_out, int out_size, void* d_ws, size_t ws_size,
                              hipStream_t stream) {
    const float* x = (const float*)d_in[0];   // (4,4096,4096) fp32
    const float* w = (const float*)d_in[1];   // (64,4096) fp32
    float* out  = (float*)d_out;              // 32768 scores + 32768 float-encoded indices
    float* part = (float*)d_ws;               // KSPLIT*TOKENS*NEXP*4 = 16.8 MB
    // packed W fragment planes right after part: 128*8*64*16B = 1 MB
    uint4* wpk = (uint4*)((char*)d_ws + (size_t)KSPLIT * TOKENS * NEXP * sizeof(float));

    pack_w_kernel<<<NCHUNK_G, 256, 0, stream>>>(w, wpk);
    router_gemm_kernel<<<(TOKENS / TB) * KSPLIT, 512, 0, stream>>>(x, wpk, part);
    topk_kernel<<<TOKENS / 4, 256, 0, stream>>>(part, out);
}